// Round 15
// baseline (35.253 us; speedup 1.0000x reference)
//
#include <hip/hip_runtime.h>
#include <hip/hip_fp16.h>

// Box-log-edge, v15: v13 (1-wave blocks, best) + packed-f32 Phase B.
// Each lane processes rows (ty, ty+8) as the two components of float2 ->
// all sliding-window adds become v_pk_add_f32 (halves the add bucket).
// Phase A (38 lanes): float2 loads, rolling 6-row sums over 26 rows ->
//   S6[0..20] (+0.06) and full11[0..15] (+0.11), fp16. bot6[r] == S6[r+5].
// Phase B (64 lanes, 8 px x 2 rows each): paired 20-half loads, packed
//   sliding windows, log-domain ratio + L2 norm, 4x float4 stores.

#define N   512
#define SH  80            // LDS row stride in halfs (160B)
#define LN2 0.69314718056f

typedef __fp16 h2  __attribute__((ext_vector_type(2)));
typedef __fp16 h4v __attribute__((ext_vector_type(4)));
typedef __fp16 h8v __attribute__((ext_vector_type(8)));

__device__ __forceinline__ float2 f2add(float2 a, float2 b){ return make_float2(a.x+b.x, a.y+b.y); }
__device__ __forceinline__ float2 f2sub(float2 a, float2 b){ return make_float2(a.x-b.x, a.y-b.y); }

// Paired load: T[i] = { arr[b0+i], arr[b1+i] } for i in 0..19, registers only.
__device__ __forceinline__ void load20pair(const __half* __restrict__ arr, int b0, int b1,
                                           float2* __restrict__ T) {
    h8v a0 = *(const h8v*)(arr + b0);
    h8v a1 = *(const h8v*)(arr + b1);
    h8v b0v = *(const h8v*)(arr + b0 + 8);
    h8v b1v = *(const h8v*)(arr + b1 + 8);
    h4v c0 = *(const h4v*)(arr + b0 + 16);
    h4v c1 = *(const h4v*)(arr + b1 + 16);
    #pragma unroll
    for (int j = 0; j < 8; ++j) T[j]      = make_float2((float)a0[j],  (float)a1[j]);
    #pragma unroll
    for (int j = 0; j < 8; ++j) T[8 + j]  = make_float2((float)b0v[j], (float)b1v[j]);
    #pragma unroll
    for (int j = 0; j < 4; ++j) T[16 + j] = make_float2((float)c0[j],  (float)c1[j]);
}

__global__ __launch_bounds__(64, 4) void boxlog_kernel(
    const float* __restrict__ x, float* __restrict__ out)
{
    __shared__ __align__(16) __half S6A [21*SH];   // S6[r] = padded rows r..r+5 (+0.06)
    __shared__ __align__(16) __half fulA[16*SH];   // full11[r] = rows r..r+10 (+0.11)

    const int lane = threadIdx.x;
    // XCD-aware swizzle over 16384 blocks: each XCD gets 8 contiguous images
    const int wg  = blockIdx.x;
    const int sw  = (wg & 7) * 2048 + (wg >> 3);
    const int bz  = sw >> 8;          // image 0..63
    const int rem = sw & 255;
    const int by  = rem >> 3;         // 0..31 (16-row tiles)
    const int bx  = rem & 7;          // 0..7  (64-col tiles)
    const int X0 = bx * 64, Y0 = by * 16;
    const float* __restrict__ xb   = x   + (size_t)bz * ((size_t)N * N);
    float* __restrict__       outb = out + (size_t)bz * ((size_t)N * N);

    // ---------------- Phase A: rolling S6 + full11 (fp16 to LDS) ------------
    if (lane < 38) {
        const int gc = X0 - 6 + 2 * lane;  // even -> 8B-aligned float2

        auto body = [&](auto loadrow) {
            float2 t[26];
            #pragma unroll
            for (int j = 0; j < 11; ++j) t[j] = loadrow(j);
            float2 lo = f2add(f2add(f2add(t[0],t[1]), f2add(t[2],t[3])), f2add(t[4],t[5]));
            float2 hi = f2add(f2add(f2add(t[5],t[6]), f2add(t[7],t[8])), f2add(t[9],t[10]));
            {
                float2 fv = f2sub(f2add(lo, hi), t[5]);
                *(h2*)&S6A [2 * lane] = __builtin_amdgcn_cvt_pkrtz(lo.x + 0.06f, lo.y + 0.06f);
                *(h2*)&fulA[2 * lane] = __builtin_amdgcn_cvt_pkrtz(fv.x + 0.11f, fv.y + 0.11f);
            }
            #pragma unroll
            for (int k = 1; k < 21; ++k) {
                if (k < 16) t[k+10] = loadrow(k + 10);
                lo = f2sub(f2add(lo, t[k+5]), t[k-1]);
                *(h2*)&S6A[k * SH + 2 * lane] = __builtin_amdgcn_cvt_pkrtz(lo.x + 0.06f, lo.y + 0.06f);
                if (k < 16) {
                    hi = f2sub(f2add(hi, t[k+10]), t[k+4]);
                    float2 fv = f2sub(f2add(lo, hi), t[k+5]);
                    *(h2*)&fulA[k * SH + 2 * lane] = __builtin_amdgcn_cvt_pkrtz(fv.x + 0.11f, fv.y + 0.11f);
                }
            }
        };

        if (by >= 1 && by <= 30 && bx >= 1 && bx <= 6) {
            body([&](int j) {
                return *(const float2*)(xb + (size_t)(Y0 - 5 + j) * N + gc);
            });
        } else {
            const bool vec = (gc >= 0) && (gc <= N - 2);
            body([&](int j) {
                int gr = Y0 - 5 + j;
                gr = gr < 0 ? -gr : (gr > N-1 ? 2*(N-1) - gr : gr);
                const float* rowp = xb + (size_t)gr * N;
                if (vec) return *(const float2*)(rowp + gc);
                int c0 = gc, c1 = gc + 1;
                c0 = c0 < 0 ? -c0 : (c0 > N-1 ? 2*(N-1) - c0 : c0);
                c1 = c1 < 0 ? -c1 : (c1 > N-1 ? 2*(N-1) - c1 : c1);
                return make_float2(rowp[c0], rowp[c1]);
            });
        }
    }
    __syncthreads();   // single-wave block: in-wave waitcnt only

    // ---------------- Phase B: packed 2-row sliding windows ------------------
    // Lane handles rows (ty, ty+8) as float2 components; 8 px strip at 8*tx.
    // T[i] <-> local col 8*tx + i ; out col o = 8*tx+p uses window T[p+1..p+11]
    const int tx = lane & 7;      // 8 strips of 8 px
    const int ty = lane >> 3;     // 0..7
    const int b0 = ty * SH + 8 * tx;
    const int b1 = (ty + 8) * SH + 8 * tx;

    float2 gy1[8], ly[8];
    {   // top6 = S6[row] -> gy1 windows (11-wide), both rows packed
        float2 T[20];
        load20pair(S6A, b0, b1, T);
        float2 g = f2add(f2add(f2add(f2add(T[1],T[2]), f2add(T[3],T[4])),
                               f2add(f2add(T[5],T[6]), f2add(T[7],T[8]))),
                         f2add(f2add(T[9],T[10]), T[11]));
        gy1[0] = g;
        #pragma unroll
        for (int p = 1; p < 8; ++p) { g = f2add(g, f2sub(T[p+11], T[p])); gy1[p] = g; }
    }
    {   // bot6 = S6[row+5] -> gy2 windows, fold into log ratio per component
        float2 T[20];
        load20pair(S6A, b0 + 5*SH, b1 + 5*SH, T);
        float2 g = f2add(f2add(f2add(f2add(T[1],T[2]), f2add(T[3],T[4])),
                               f2add(f2add(T[5],T[6]), f2add(T[7],T[8]))),
                         f2add(f2add(T[9],T[10]), T[11]));
        ly[0] = make_float2(__builtin_amdgcn_logf(gy1[0].x) - __builtin_amdgcn_logf(g.x),
                            __builtin_amdgcn_logf(gy1[0].y) - __builtin_amdgcn_logf(g.y));
        #pragma unroll
        for (int p = 1; p < 8; ++p) {
            g = f2add(g, f2sub(T[p+11], T[p]));
            ly[p] = make_float2(__builtin_amdgcn_logf(gy1[p].x) - __builtin_amdgcn_logf(g.x),
                                __builtin_amdgcn_logf(gy1[p].y) - __builtin_amdgcn_logf(g.y));
        }
    }
    {   // full11 -> gx window pair (6-wide), combine + store, both rows packed
        float2 T[20];
        load20pair(fulA, b0, b1, T);
        float2 g1 = f2add(f2add(f2add(T[1],T[2]), f2add(T[3],T[4])), f2add(T[5],T[6]));
        float2 g2 = f2add(f2add(f2add(T[6],T[7]), f2add(T[8],T[9])), f2add(T[10],T[11]));
        float r0[8], r1[8];
        #pragma unroll
        for (int p = 0; p < 8; ++p) {
            if (p) {
                g1 = f2add(g1, f2sub(T[p+6],  T[p]));
                g2 = f2add(g2, f2sub(T[p+11], T[p+5]));
            }
            float2 lx = make_float2(__builtin_amdgcn_logf(g1.x) - __builtin_amdgcn_logf(g2.x),
                                    __builtin_amdgcn_logf(g1.y) - __builtin_amdgcn_logf(g2.y));
            float2 v  = make_float2(lx.x*lx.x + ly[p].x*ly[p].x,
                                    lx.y*lx.y + ly[p].y*ly[p].y);
            r0[p] = LN2 * __builtin_amdgcn_sqrtf(v.x);
            r1[p] = LN2 * __builtin_amdgcn_sqrtf(v.y);
        }
        float* op0 = outb + (size_t)(Y0 + ty)     * N + X0 + tx * 8;
        float* op1 = outb + (size_t)(Y0 + ty + 8) * N + X0 + tx * 8;
        *(float4*)op0       = make_float4(r0[0], r0[1], r0[2], r0[3]);
        *(float4*)(op0 + 4) = make_float4(r0[4], r0[5], r0[6], r0[7]);
        *(float4*)op1       = make_float4(r1[0], r1[1], r1[2], r1[3]);
        *(float4*)(op1 + 4) = make_float4(r1[4], r1[5], r1[6], r1[7]);
    }
}

extern "C" void kernel_launch(void* const* d_in, const int* in_sizes, int n_in,
                              void* d_out, int out_size, void* d_ws, size_t ws_size,
                              hipStream_t stream) {
    const float* x = (const float*)d_in[0];  // (64,1,512,512) fp32
    float* out = (float*)d_out;              // (64,1,512,512) fp32
    dim3 grid(8 * 32 * 64);                  // 64x16 tiles, swizzled in-kernel
    dim3 block(64);
    boxlog_kernel<<<grid, block, 0, stream>>>(x, out);
}

// Round 16
// 34.596 us; speedup vs baseline: 1.0190x; 1.0190x over previous
//
#include <hip/hip_runtime.h>
#include <hip/hip_fp16.h>

// Box-log-edge, v16: v13 + shared-log algebra.
//  gy2(row)=gy1(row+5): M[r][c]=log2(win11(S6[r],c)) computed once (21 rows),
//    ly = M[row]-M[row+5]; M exchanged via LDS unioned over dead S6A.
//  gx2(o)=gx1(o+5):   L[o]=log2(win6(full11,o+1)); lane computes 13 cols
//    (own 8 + 5 overlap) fully in registers; lx = L[p]-L[p+5].
// Phase A (38 lanes): rolling 6-row sums -> S6[0..20](+0.06), full11[0..15](+0.11), fp16.
// B1: M rows {ty,ty+8,ty+16<21} (24 logs) + L rows {ty,ty+8} (26 logs), regs.
// B1b: store M f32 over S6A region. B2: ly/lx subs + 16 sqrt, float4 stores.

#define N   512
#define SH  80            // S6A/fulA stride in halfs
#define MS  68            // M stride in floats (68%32=4 -> even bank quads)
#define LN2 0.69314718056f

typedef __fp16 h2  __attribute__((ext_vector_type(2)));
typedef __fp16 h4v __attribute__((ext_vector_type(4)));
typedef __fp16 h8v __attribute__((ext_vector_type(8)));

__device__ __forceinline__ float2 f2add(float2 a, float2 b){ return make_float2(a.x+b.x, a.y+b.y); }
__device__ __forceinline__ float2 f2sub(float2 a, float2 b){ return make_float2(a.x-b.x, a.y-b.y); }

// Load halfs [base .. base+19] into f32 t[0..19], registers only.
__device__ __forceinline__ void load20(const __half* __restrict__ arr, int base, float* __restrict__ t) {
    h8v a = *(const h8v*)(arr + base);
    h8v b = *(const h8v*)(arr + base + 8);
    h4v c = *(const h4v*)(arr + base + 16);
    #pragma unroll
    for (int j = 0; j < 8; ++j) t[j]      = (float)a[j];
    #pragma unroll
    for (int j = 0; j < 8; ++j) t[8 + j]  = (float)b[j];
    #pragma unroll
    for (int j = 0; j < 4; ++j) t[16 + j] = (float)c[j];
}

__global__ __launch_bounds__(64, 4) void boxlog_kernel(
    const float* __restrict__ x, float* __restrict__ out)
{
    // region1: S6A fp16 [21*SH] (3360B) unioned with M f32 [21*MS] (5712B)
    __shared__ __align__(16) unsigned char reg1[21 * MS * 4];
    __shared__ __align__(16) __half fulA[16 * SH];          // full11 (+0.11)
    __half* S6A = (__half*)reg1;                            // S6 (+0.06)
    float*  Mld = (float*)reg1;                             // M after B1b

    const int lane = threadIdx.x;
    // XCD-aware swizzle over 16384 blocks: each XCD gets 8 contiguous images
    const int wg  = blockIdx.x;
    const int sw  = (wg & 7) * 2048 + (wg >> 3);
    const int bz  = sw >> 8;          // image 0..63
    const int rem = sw & 255;
    const int by  = rem >> 3;         // 0..31 (16-row tiles)
    const int bx  = rem & 7;          // 0..7  (64-col tiles)
    const int X0 = bx * 64, Y0 = by * 16;
    const float* __restrict__ xb   = x   + (size_t)bz * ((size_t)N * N);
    float* __restrict__       outb = out + (size_t)bz * ((size_t)N * N);

    // ---------------- Phase A: rolling S6 + full11 (fp16 to LDS) ------------
    if (lane < 38) {
        const int gc = X0 - 6 + 2 * lane;  // even -> 8B-aligned float2

        auto body = [&](auto loadrow) {
            float2 t[26];
            #pragma unroll
            for (int j = 0; j < 11; ++j) t[j] = loadrow(j);
            float2 lo = f2add(f2add(f2add(t[0],t[1]), f2add(t[2],t[3])), f2add(t[4],t[5]));
            float2 hi = f2add(f2add(f2add(t[5],t[6]), f2add(t[7],t[8])), f2add(t[9],t[10]));
            {
                float2 fv = f2sub(f2add(lo, hi), t[5]);
                *(h2*)&S6A [2 * lane] = __builtin_amdgcn_cvt_pkrtz(lo.x + 0.06f, lo.y + 0.06f);
                *(h2*)&fulA[2 * lane] = __builtin_amdgcn_cvt_pkrtz(fv.x + 0.11f, fv.y + 0.11f);
            }
            #pragma unroll
            for (int k = 1; k < 21; ++k) {
                if (k < 16) t[k+10] = loadrow(k + 10);
                lo = f2sub(f2add(lo, t[k+5]), t[k-1]);
                *(h2*)&S6A[k * SH + 2 * lane] = __builtin_amdgcn_cvt_pkrtz(lo.x + 0.06f, lo.y + 0.06f);
                if (k < 16) {
                    hi = f2sub(f2add(hi, t[k+10]), t[k+4]);
                    float2 fv = f2sub(f2add(lo, hi), t[k+5]);
                    *(h2*)&fulA[k * SH + 2 * lane] = __builtin_amdgcn_cvt_pkrtz(fv.x + 0.11f, fv.y + 0.11f);
                }
            }
        };

        if (by >= 1 && by <= 30 && bx >= 1 && bx <= 6) {
            body([&](int j) {
                return *(const float2*)(xb + (size_t)(Y0 - 5 + j) * N + gc);
            });
        } else {
            const bool vec = (gc >= 0) && (gc <= N - 2);
            body([&](int j) {
                int gr = Y0 - 5 + j;
                gr = gr < 0 ? -gr : (gr > N-1 ? 2*(N-1) - gr : gr);
                const float* rowp = xb + (size_t)gr * N;
                if (vec) return *(const float2*)(rowp + gc);
                int c0 = gc, c1 = gc + 1;
                c0 = c0 < 0 ? -c0 : (c0 > N-1 ? 2*(N-1) - c0 : c0);
                c1 = c1 < 0 ? -c1 : (c1 > N-1 ? 2*(N-1) - c1 : c1);
                return make_float2(rowp[c0], rowp[c1]);
            });
        }
    }
    __syncthreads();

    const int tx = lane & 7;      // 8-px strip
    const int ty = lane >> 3;     // 0..7

    // ---------------- B1: M and L log fields into registers ------------------
    float Ma[8], Mb[8], Mc[8];
    auto mchunk = [&](int r, float* __restrict__ m) {
        float t[20];
        load20(S6A, r * SH + 8 * tx, t);
        float g = ((t[1]+t[2])+(t[3]+t[4]))+((t[5]+t[6])+(t[7]+t[8]))+((t[9]+t[10])+t[11]);
        m[0] = __builtin_amdgcn_logf(g);
        #pragma unroll
        for (int p = 1; p < 8; ++p) { g += t[p+11] - t[p]; m[p] = __builtin_amdgcn_logf(g); }
    };
    mchunk(ty, Ma);
    mchunk(ty + 8, Mb);
    if (ty < 5) mchunk(ty + 16, Mc);

    float La[13], Lb[13];
    auto lchunk = [&](int r, float* __restrict__ l) {
        float t[20];
        load20(fulA, r * SH + 8 * tx, t);
        float g = ((t[1]+t[2])+(t[3]+t[4]))+(t[5]+t[6]);
        l[0] = __builtin_amdgcn_logf(g);
        #pragma unroll
        for (int p = 1; p < 13; ++p) { g += t[p+6] - t[p]; l[p] = __builtin_amdgcn_logf(g); }
    };
    lchunk(ty, La);
    lchunk(ty + 8, Lb);

    __syncthreads();   // all S6A reads complete before M overwrites region1

    // ---------------- B1b: publish M (f32) over the dead S6A region ----------
    *(float4*)&Mld[ty * MS + 8 * tx]           = make_float4(Ma[0], Ma[1], Ma[2], Ma[3]);
    *(float4*)&Mld[ty * MS + 8 * tx + 4]       = make_float4(Ma[4], Ma[5], Ma[6], Ma[7]);
    *(float4*)&Mld[(ty + 8) * MS + 8 * tx]     = make_float4(Mb[0], Mb[1], Mb[2], Mb[3]);
    *(float4*)&Mld[(ty + 8) * MS + 8 * tx + 4] = make_float4(Mb[4], Mb[5], Mb[6], Mb[7]);
    if (ty < 5) {
        *(float4*)&Mld[(ty + 16) * MS + 8 * tx]     = make_float4(Mc[0], Mc[1], Mc[2], Mc[3]);
        *(float4*)&Mld[(ty + 16) * MS + 8 * tx + 4] = make_float4(Mc[4], Mc[5], Mc[6], Mc[7]);
    }
    __syncthreads();

    // ---------------- B2: combine (subs + sqrt only) --------------------------
    auto strip = [&](int row, const float* __restrict__ mS, const float* __restrict__ lS) {
        float mB[8];
        *(float4*)&mB[0] = *(const float4*)&Mld[(row + 5) * MS + 8 * tx];
        *(float4*)&mB[4] = *(const float4*)&Mld[(row + 5) * MS + 8 * tx + 4];
        float r8[8];
        #pragma unroll
        for (int p = 0; p < 8; ++p) {
            float ly = mS[p] - mB[p];
            float lx = lS[p] - lS[p + 5];
            r8[p] = LN2 * __builtin_amdgcn_sqrtf(lx * lx + ly * ly);
        }
        float* op = outb + (size_t)(Y0 + row) * N + X0 + tx * 8;
        *(float4*)op       = make_float4(r8[0], r8[1], r8[2], r8[3]);
        *(float4*)(op + 4) = make_float4(r8[4], r8[5], r8[6], r8[7]);
    };
    strip(ty,     Ma, La);
    strip(ty + 8, Mb, Lb);
}

extern "C" void kernel_launch(void* const* d_in, const int* in_sizes, int n_in,
                              void* d_out, int out_size, void* d_ws, size_t ws_size,
                              hipStream_t stream) {
    const float* x = (const float*)d_in[0];  // (64,1,512,512) fp32
    float* out = (float*)d_out;              // (64,1,512,512) fp32
    dim3 grid(8 * 32 * 64);                  // 64x16 tiles, swizzled in-kernel
    dim3 block(64);
    boxlog_kernel<<<grid, block, 0, stream>>>(x, out);
}

// Round 17
// 34.584 us; speedup vs baseline: 1.0194x; 1.0003x over previous
//
#include <hip/hip_runtime.h>

// Box-log-edge, v17: v16 algebra + f32 LDS in chunk-major layout (kills all
// f16 cvts; layout chosen so ds_read_b128 is 2-way-bank = free).
//  S6f [19 chunks][21 rows][4 f32]  (chunk stride 84 floats)   \ region1 (M
//  M   [21][68] f32 unions over S6f after its last read        /  overwrite)
//  fulf[19 chunks][17 rows][4 f32]  (chunk stride 68 floats, row-padded)
// Phase A (38 lanes): rolling 6-row sums -> S6[0..20](+0.06), full11[0..15](+0.11).
// B1: M = log2(win11(S6)) rows {ty,ty+8,ty+16<21}; L = log2(win6(ful)) 13 cols, regs.
// B1b: publish M over S6f. B2: ly=M[r]-M[r+5], lx=L[p]-L[p+5], sqrt, stores.

#define N   512
#define CS6 84            // S6f chunk stride in floats (21 rows x 4)
#define CFL 68            // fulf chunk stride in floats (17 rows x 4, padded)
#define MS  68            // M row stride in floats
#define LN2 0.69314718056f

__device__ __forceinline__ float2 f2add(float2 a, float2 b){ return make_float2(a.x+b.x, a.y+b.y); }
__device__ __forceinline__ float2 f2sub(float2 a, float2 b){ return make_float2(a.x-b.x, a.y-b.y); }

// Load cols [8tx .. 8tx+19] of row r from a chunk-major array: 5x b128.
__device__ __forceinline__ void load20cm(const float* __restrict__ arr, int tx, int r,
                                         int cstride, float* __restrict__ t) {
    #pragma unroll
    for (int i = 0; i < 5; ++i)
        *(float4*)&t[4*i] = *(const float4*)&arr[(2*tx + i) * cstride + r * 4];
}

__global__ __launch_bounds__(64, 4) void boxlog_kernel(
    const float* __restrict__ x, float* __restrict__ out)
{
    // region1: S6f (19*84*4B = 6384B) unioned with M (21*68*4B = 5712B)
    __shared__ __align__(16) float reg1[19 * CS6];
    __shared__ __align__(16) float fulf[19 * CFL];
    float* S6f = reg1;
    float* Mld = reg1;

    const int lane = threadIdx.x;
    // XCD-aware swizzle over 16384 blocks: each XCD gets 8 contiguous images
    const int wg  = blockIdx.x;
    const int sw  = (wg & 7) * 2048 + (wg >> 3);
    const int bz  = sw >> 8;          // image 0..63
    const int rem = sw & 255;
    const int by  = rem >> 3;         // 0..31 (16-row tiles)
    const int bx  = rem & 7;          // 0..7  (64-col tiles)
    const int X0 = bx * 64, Y0 = by * 16;
    const float* __restrict__ xb   = x   + (size_t)bz * ((size_t)N * N);
    float* __restrict__       outb = out + (size_t)bz * ((size_t)N * N);

    // ---------------- Phase A: rolling S6 + full11 (f32, chunk-major) -------
    // 38 lanes x 2 cols (local cols 2l..2l+1 <-> global X0-6+2l), 26 padded rows.
    if (lane < 38) {
        const int gc = X0 - 6 + 2 * lane;       // even -> 8B-aligned float2
        const int c6 = (lane >> 1) * CS6 + 2 * (lane & 1);   // S6f float2 base
        const int cf = (lane >> 1) * CFL + 2 * (lane & 1);   // fulf float2 base

        auto body = [&](auto loadrow) {
            float2 t[26];
            #pragma unroll
            for (int j = 0; j < 11; ++j) t[j] = loadrow(j);
            float2 lo = f2add(f2add(f2add(t[0],t[1]), f2add(t[2],t[3])), f2add(t[4],t[5]));
            float2 hi = f2add(f2add(f2add(t[5],t[6]), f2add(t[7],t[8])), f2add(t[9],t[10]));
            {
                float2 fv = f2sub(f2add(lo, hi), t[5]);
                *(float2*)&S6f [c6] = make_float2(lo.x + 0.06f, lo.y + 0.06f);
                *(float2*)&fulf[cf] = make_float2(fv.x + 0.11f, fv.y + 0.11f);
            }
            #pragma unroll
            for (int k = 1; k < 21; ++k) {
                if (k < 16) t[k+10] = loadrow(k + 10);
                lo = f2sub(f2add(lo, t[k+5]), t[k-1]);
                *(float2*)&S6f[c6 + 4*k] = make_float2(lo.x + 0.06f, lo.y + 0.06f);
                if (k < 16) {
                    hi = f2sub(f2add(hi, t[k+10]), t[k+4]);
                    float2 fv = f2sub(f2add(lo, hi), t[k+5]);
                    *(float2*)&fulf[cf + 4*k] = make_float2(fv.x + 0.11f, fv.y + 0.11f);
                }
            }
        };

        if (by >= 1 && by <= 30 && bx >= 1 && bx <= 6) {
            body([&](int j) {
                return *(const float2*)(xb + (size_t)(Y0 - 5 + j) * N + gc);
            });
        } else {
            const bool vec = (gc >= 0) && (gc <= N - 2);
            body([&](int j) {
                int gr = Y0 - 5 + j;
                gr = gr < 0 ? -gr : (gr > N-1 ? 2*(N-1) - gr : gr);
                const float* rowp = xb + (size_t)gr * N;
                if (vec) return *(const float2*)(rowp + gc);
                int c0 = gc, c1 = gc + 1;
                c0 = c0 < 0 ? -c0 : (c0 > N-1 ? 2*(N-1) - c0 : c0);
                c1 = c1 < 0 ? -c1 : (c1 > N-1 ? 2*(N-1) - c1 : c1);
                return make_float2(rowp[c0], rowp[c1]);
            });
        }
    }
    __syncthreads();

    const int tx = lane & 7;      // 8-px strip
    const int ty = lane >> 3;     // 0..7

    // ---------------- B1: M and L log fields into registers ------------------
    float Ma[8], Mb[8], Mc[8];
    auto mchunk = [&](int r, float* __restrict__ m) {
        float t[20];
        load20cm(S6f, tx, r, CS6, t);
        float g = ((t[1]+t[2])+(t[3]+t[4]))+((t[5]+t[6])+(t[7]+t[8]))+((t[9]+t[10])+t[11]);
        m[0] = __builtin_amdgcn_logf(g);
        #pragma unroll
        for (int p = 1; p < 8; ++p) { g += t[p+11] - t[p]; m[p] = __builtin_amdgcn_logf(g); }
    };
    mchunk(ty, Ma);
    mchunk(ty + 8, Mb);
    if (ty < 5) mchunk(ty + 16, Mc);

    float La[13], Lb[13];
    auto lchunk = [&](int r, float* __restrict__ l) {
        float t[20];
        load20cm(fulf, tx, r, CFL, t);
        float g = ((t[1]+t[2])+(t[3]+t[4]))+(t[5]+t[6]);
        l[0] = __builtin_amdgcn_logf(g);
        #pragma unroll
        for (int p = 1; p < 13; ++p) { g += t[p+6] - t[p]; l[p] = __builtin_amdgcn_logf(g); }
    };
    lchunk(ty, La);
    lchunk(ty + 8, Lb);

    __syncthreads();   // all S6f reads complete before M overwrites region1

    // ---------------- B1b: publish M (f32) over the dead S6f region ----------
    *(float4*)&Mld[ty * MS + 8 * tx]           = make_float4(Ma[0], Ma[1], Ma[2], Ma[3]);
    *(float4*)&Mld[ty * MS + 8 * tx + 4]       = make_float4(Ma[4], Ma[5], Ma[6], Ma[7]);
    *(float4*)&Mld[(ty + 8) * MS + 8 * tx]     = make_float4(Mb[0], Mb[1], Mb[2], Mb[3]);
    *(float4*)&Mld[(ty + 8) * MS + 8 * tx + 4] = make_float4(Mb[4], Mb[5], Mb[6], Mb[7]);
    if (ty < 5) {
        *(float4*)&Mld[(ty + 16) * MS + 8 * tx]     = make_float4(Mc[0], Mc[1], Mc[2], Mc[3]);
        *(float4*)&Mld[(ty + 16) * MS + 8 * tx + 4] = make_float4(Mc[4], Mc[5], Mc[6], Mc[7]);
    }
    __syncthreads();

    // ---------------- B2: combine (subs + sqrt only) --------------------------
    auto strip = [&](int row, const float* __restrict__ mS, const float* __restrict__ lS) {
        float mB[8];
        *(float4*)&mB[0] = *(const float4*)&Mld[(row + 5) * MS + 8 * tx];
        *(float4*)&mB[4] = *(const float4*)&Mld[(row + 5) * MS + 8 * tx + 4];
        float r8[8];
        #pragma unroll
        for (int p = 0; p < 8; ++p) {
            float ly = mS[p] - mB[p];
            float lx = lS[p] - lS[p + 5];
            r8[p] = LN2 * __builtin_amdgcn_sqrtf(lx * lx + ly * ly);
        }
        float* op = outb + (size_t)(Y0 + row) * N + X0 + tx * 8;
        *(float4*)op       = make_float4(r8[0], r8[1], r8[2], r8[3]);
        *(float4*)(op + 4) = make_float4(r8[4], r8[5], r8[6], r8[7]);
    };
    strip(ty,     Ma, La);
    strip(ty + 8, Mb, Lb);
}

extern "C" void kernel_launch(void* const* d_in, const int* in_sizes, int n_in,
                              void* d_out, int out_size, void* d_ws, size_t ws_size,
                              hipStream_t stream) {
    const float* x = (const float*)d_in[0];  // (64,1,512,512) fp32
    float* out = (float*)d_out;              // (64,1,512,512) fp32
    dim3 grid(8 * 32 * 64);                  // 64x16 tiles, swizzled in-kernel
    dim3 block(64);
    boxlog_kernel<<<grid, block, 0, stream>>>(x, out);
}

// Round 18
// 33.596 us; speedup vs baseline: 1.0493x; 1.0294x over previous
//
#include <hip/hip_runtime.h>

// Box-log-edge, v18: v17 + Phase-A full load hoist (all 26 row loads in
// flight before any arithmetic; 1-wave blocks + VGPR cap 128 make it fit
// where v10's (256,7) attempt spilled).
//  S6f [19 chunks][21 rows][4 f32] (chunk stride 84) \ region1, M overwrites
//  M   [21][68] f32                                  /
//  fulf[19 chunks][17 rows][4 f32] (chunk stride 68)
// B1: M = log(win11(S6)) rows {ty,ty+8,ty+16<21}; L = log(win6(ful)) 13 cols.
// B2: ly=M[r]-M[r+5], lx=L[p]-L[p+5], sqrt, float4 stores.

#define N   512
#define CS6 84            // S6f chunk stride in floats (21 rows x 4)
#define CFL 68            // fulf chunk stride in floats (17 rows x 4, padded)
#define MS  68            // M row stride in floats
#define LN2 0.69314718056f

__device__ __forceinline__ float2 f2add(float2 a, float2 b){ return make_float2(a.x+b.x, a.y+b.y); }
__device__ __forceinline__ float2 f2sub(float2 a, float2 b){ return make_float2(a.x-b.x, a.y-b.y); }

// Load cols [8tx .. 8tx+19] of row r from a chunk-major array: 5x b128.
__device__ __forceinline__ void load20cm(const float* __restrict__ arr, int tx, int r,
                                         int cstride, float* __restrict__ t) {
    #pragma unroll
    for (int i = 0; i < 5; ++i)
        *(float4*)&t[4*i] = *(const float4*)&arr[(2*tx + i) * cstride + r * 4];
}

__global__ __launch_bounds__(64, 4) void boxlog_kernel(
    const float* __restrict__ x, float* __restrict__ out)
{
    // region1: S6f (19*84*4B = 6384B) unioned with M (21*68*4B = 5712B)
    __shared__ __align__(16) float reg1[19 * CS6];
    __shared__ __align__(16) float fulf[19 * CFL];
    float* S6f = reg1;
    float* Mld = reg1;

    const int lane = threadIdx.x;
    // XCD-aware swizzle over 16384 blocks: each XCD gets 8 contiguous images
    const int wg  = blockIdx.x;
    const int sw  = (wg & 7) * 2048 + (wg >> 3);
    const int bz  = sw >> 8;          // image 0..63
    const int rem = sw & 255;
    const int by  = rem >> 3;         // 0..31 (16-row tiles)
    const int bx  = rem & 7;          // 0..7  (64-col tiles)
    const int X0 = bx * 64, Y0 = by * 16;
    const float* __restrict__ xb   = x   + (size_t)bz * ((size_t)N * N);
    float* __restrict__       outb = out + (size_t)bz * ((size_t)N * N);

    // ---------------- Phase A: hoisted loads + rolling sums (f32 LDS) -------
    // 38 lanes x 2 cols (local cols 2l..2l+1 <-> global X0-6+2l), 26 padded rows.
    if (lane < 38) {
        const int gc = X0 - 6 + 2 * lane;       // even -> 8B-aligned float2
        const int c6 = (lane >> 1) * CS6 + 2 * (lane & 1);   // S6f float2 base
        const int cf = (lane >> 1) * CFL + 2 * (lane & 1);   // fulf float2 base

        auto body = [&](auto loadrow) {
            float2 t[26];
            #pragma unroll
            for (int j = 0; j < 26; ++j) t[j] = loadrow(j);   // ALL loads in flight
            __builtin_amdgcn_sched_barrier(0);                // no sinking past here
            float2 lo = f2add(f2add(f2add(t[0],t[1]), f2add(t[2],t[3])), f2add(t[4],t[5]));
            float2 hi = f2add(f2add(f2add(t[5],t[6]), f2add(t[7],t[8])), f2add(t[9],t[10]));
            {
                float2 fv = f2sub(f2add(lo, hi), t[5]);
                *(float2*)&S6f [c6] = make_float2(lo.x + 0.06f, lo.y + 0.06f);
                *(float2*)&fulf[cf] = make_float2(fv.x + 0.11f, fv.y + 0.11f);
            }
            #pragma unroll
            for (int k = 1; k < 21; ++k) {
                lo = f2sub(f2add(lo, t[k+5]), t[k-1]);
                *(float2*)&S6f[c6 + 4*k] = make_float2(lo.x + 0.06f, lo.y + 0.06f);
                if (k < 16) {
                    hi = f2sub(f2add(hi, t[k+10]), t[k+4]);
                    float2 fv = f2sub(f2add(lo, hi), t[k+5]);
                    *(float2*)&fulf[cf + 4*k] = make_float2(fv.x + 0.11f, fv.y + 0.11f);
                }
            }
        };

        if (by >= 1 && by <= 30 && bx >= 1 && bx <= 6) {
            body([&](int j) {
                return *(const float2*)(xb + (size_t)(Y0 - 5 + j) * N + gc);
            });
        } else {
            const bool vec = (gc >= 0) && (gc <= N - 2);
            body([&](int j) {
                int gr = Y0 - 5 + j;
                gr = gr < 0 ? -gr : (gr > N-1 ? 2*(N-1) - gr : gr);
                const float* rowp = xb + (size_t)gr * N;
                if (vec) return *(const float2*)(rowp + gc);
                int c0 = gc, c1 = gc + 1;
                c0 = c0 < 0 ? -c0 : (c0 > N-1 ? 2*(N-1) - c0 : c0);
                c1 = c1 < 0 ? -c1 : (c1 > N-1 ? 2*(N-1) - c1 : c1);
                return make_float2(rowp[c0], rowp[c1]);
            });
        }
    }
    __syncthreads();

    const int tx = lane & 7;      // 8-px strip
    const int ty = lane >> 3;     // 0..7

    // ---------------- B1: M and L log fields into registers ------------------
    float Ma[8], Mb[8], Mc[8];
    auto mchunk = [&](int r, float* __restrict__ m) {
        float t[20];
        load20cm(S6f, tx, r, CS6, t);
        float g = ((t[1]+t[2])+(t[3]+t[4]))+((t[5]+t[6])+(t[7]+t[8]))+((t[9]+t[10])+t[11]);
        m[0] = __builtin_amdgcn_logf(g);
        #pragma unroll
        for (int p = 1; p < 8; ++p) { g += t[p+11] - t[p]; m[p] = __builtin_amdgcn_logf(g); }
    };
    mchunk(ty, Ma);
    mchunk(ty + 8, Mb);
    if (ty < 5) mchunk(ty + 16, Mc);

    float La[13], Lb[13];
    auto lchunk = [&](int r, float* __restrict__ l) {
        float t[20];
        load20cm(fulf, tx, r, CFL, t);
        float g = ((t[1]+t[2])+(t[3]+t[4]))+(t[5]+t[6]);
        l[0] = __builtin_amdgcn_logf(g);
        #pragma unroll
        for (int p = 1; p < 13; ++p) { g += t[p+6] - t[p]; l[p] = __builtin_amdgcn_logf(g); }
    };
    lchunk(ty, La);
    lchunk(ty + 8, Lb);

    __syncthreads();   // all S6f reads complete before M overwrites region1

    // ---------------- B1b: publish M (f32) over the dead S6f region ----------
    *(float4*)&Mld[ty * MS + 8 * tx]           = make_float4(Ma[0], Ma[1], Ma[2], Ma[3]);
    *(float4*)&Mld[ty * MS + 8 * tx + 4]       = make_float4(Ma[4], Ma[5], Ma[6], Ma[7]);
    *(float4*)&Mld[(ty + 8) * MS + 8 * tx]     = make_float4(Mb[0], Mb[1], Mb[2], Mb[3]);
    *(float4*)&Mld[(ty + 8) * MS + 8 * tx + 4] = make_float4(Mb[4], Mb[5], Mb[6], Mb[7]);
    if (ty < 5) {
        *(float4*)&Mld[(ty + 16) * MS + 8 * tx]     = make_float4(Mc[0], Mc[1], Mc[2], Mc[3]);
        *(float4*)&Mld[(ty + 16) * MS + 8 * tx + 4] = make_float4(Mc[4], Mc[5], Mc[6], Mc[7]);
    }
    __syncthreads();

    // ---------------- B2: combine (subs + sqrt only) --------------------------
    auto strip = [&](int row, const float* __restrict__ mS, const float* __restrict__ lS) {
        float mB[8];
        *(float4*)&mB[0] = *(const float4*)&Mld[(row + 5) * MS + 8 * tx];
        *(float4*)&mB[4] = *(const float4*)&Mld[(row + 5) * MS + 8 * tx + 4];
        float r8[8];
        #pragma unroll
        for (int p = 0; p < 8; ++p) {
            float ly = mS[p] - mB[p];
            float lx = lS[p] - lS[p + 5];
            r8[p] = LN2 * __builtin_amdgcn_sqrtf(lx * lx + ly * ly);
        }
        float* op = outb + (size_t)(Y0 + row) * N + X0 + tx * 8;
        *(float4*)op       = make_float4(r8[0], r8[1], r8[2], r8[3]);
        *(float4*)(op + 4) = make_float4(r8[4], r8[5], r8[6], r8[7]);
    };
    strip(ty,     Ma, La);
    strip(ty + 8, Mb, Lb);
}

extern "C" void kernel_launch(void* const* d_in, const int* in_sizes, int n_in,
                              void* d_out, int out_size, void* d_ws, size_t ws_size,
                              hipStream_t stream) {
    const float* x = (const float*)d_in[0];  // (64,1,512,512) fp32
    float* out = (float*)d_out;              // (64,1,512,512) fp32
    dim3 grid(8 * 32 * 64);                  // 64x16 tiles, swizzled in-kernel
    dim3 block(64);
    boxlog_kernel<<<grid, block, 0, stream>>>(x, out);
}